// Round 12
// baseline (1216.283 us; speedup 1.0000x reference)
//
#include <hip/hip_runtime.h>
#include <cmath>
#include <cstddef>

// Problem constants
#define BN_ 16
#define CN_ 512
#define TN_ 4096
#define TPAD_ 4112   // 8 zero pad rows each side (t dim) for conv halo
#define PADR_ 8

typedef float f32x4 __attribute__((ext_vector_type(4)));
typedef __bf16 bf16x8 __attribute__((ext_vector_type(8)));
typedef unsigned short u16x8 __attribute__((ext_vector_type(8)));

struct AAFilt { float g0[6]; float g1[6]; float fE[6]; float fO[6]; };

__device__ __forceinline__ unsigned short f2bf(float f) {
  unsigned u = __builtin_bit_cast(unsigned, f);
  u = (u + 0x7fffu + ((u >> 16) & 1u)) >> 16;   // RNE
  return (unsigned short)u;
}
__device__ __forceinline__ float bf2f(unsigned short h) {
  return __builtin_bit_cast(float, (unsigned)h << 16);
}

__device__ __forceinline__ void gld16(const void* g, void* l) {
  __builtin_amdgcn_global_load_lds((const __attribute__((address_space(1))) void*)g,
                                   (__attribute__((address_space(3))) void*)l,
                                   16, 0, 0);
}

// ---------------------------------------------------------------------------
// Weight prep: W[o] = g[o] * v[o] / ||v[o]||, packed bf16 as [layer][k][o][c]
// ---------------------------------------------------------------------------
__global__ __launch_bounds__(256) void prep_w(
    const float* __restrict__ vin, const float* __restrict__ gin,
    const float* __restrict__ vout, const float* __restrict__ gout,
    unsigned short* __restrict__ wpack)
{
  const int o = blockIdx.x;
  const int l = blockIdx.y;
  const int i = l >> 1, oc = l & 1;
  const float* v = (oc ? vout : vin) + (size_t)i * CN_ * CN_ * 3 + (size_t)o * CN_ * 3;
  const float g = (oc ? gout : gin)[i * CN_ + o];
  const int tid = threadIdx.x;

  float a = 0.f;
  for (int j = tid; j < 1536; j += 256) { float x = v[j]; a += x * x; }
  #pragma unroll
  for (int off = 32; off > 0; off >>= 1) a += __shfl_down(a, off);
  __shared__ float red[4];
  if ((tid & 63) == 0) red[tid >> 6] = a;
  __syncthreads();
  const float tot = red[0] + red[1] + red[2] + red[3];
  const float scale = g / sqrtf(tot);
  unsigned short* wl = wpack + (size_t)l * 3 * CN_ * CN_;
  for (int j = tid; j < 1536; j += 256) {
    int c = j / 3, k = j - 3 * c;           // v layout [o][c][k]
    wl[((size_t)k * CN_ + o) * CN_ + c] = f2bf(v[j] * scale);
  }
}

// ---------------------------------------------------------------------------
// Transpose [b][c][t] f32 -> [b][t][c] bf16  (x-chain is bf16 from here on)
// ---------------------------------------------------------------------------
__global__ __launch_bounds__(256) void transpose_in(
    const float* __restrict__ src, unsigned short* __restrict__ dst)
{
  __shared__ float tile[32][33];
  const int b = blockIdx.z, c0 = blockIdx.y * 32, t0 = blockIdx.x * 32;
  const int tx = threadIdx.x & 31, ty = threadIdx.x >> 5;   // ty 0..7
  const float* s = src + ((size_t)b * CN_ + c0) * TN_ + t0;
  #pragma unroll
  for (int j = 0; j < 32; j += 8) tile[ty + j][tx] = s[(size_t)(ty + j) * TN_ + tx];
  __syncthreads();
  unsigned short* d = dst + ((size_t)b * TN_ + t0) * CN_ + c0;
  #pragma unroll
  for (int j = 0; j < 32; j += 8) d[(size_t)(ty + j) * CN_ + tx] = f2bf(tile[tx][ty + j]);
}

// ---------------------------------------------------------------------------
// Alias-free snake activation, streaming along t. bf16 in/out. (r9, unchanged)
// ---------------------------------------------------------------------------
__global__ __launch_bounds__(512) void act_kernel(
    const unsigned short* __restrict__ src, unsigned short* __restrict__ dst,
    const float* __restrict__ alpha, const float* __restrict__ beta,
    const float* __restrict__ mask, AAFilt F)
{
  const int c = threadIdx.x;       // 0..511
  const int b = blockIdx.y;        // 0..15
  const int seg = blockIdx.x;      // 0..31
  const int t0 = seg << 7;         // 128 t per block
  const float av = expf(alpha[c]);
  const float ib = 1.0f / (expf(beta[c]) + 1e-5f);
  const unsigned short* row = src + (size_t)b * TN_ * CN_ + c;
  unsigned short* drow = dst + (size_t)b * TPAD_ * CN_ + c;
  const float* mrow = mask + (size_t)b * TN_;

  if (seg == 0)  { for (int p = 0; p < PADR_; ++p) drow[(size_t)p * CN_] = 0; }
  if (seg == 31) { for (int p = 0; p < PADR_; ++p) drow[(size_t)(TPAD_ - PADR_ + p) * CN_] = 0; }

  auto ldx = [&](int t) -> float {
    t = t < 0 ? 0 : (t > TN_ - 1 ? TN_ - 1 : t);
    return bf2f(row[(size_t)t * CN_]);
  };

  float xw[6];
  #pragma unroll
  for (int j = 0; j < 6; ++j) xw[j] = ldx(t0 - 5 + j);
  float sE[6], sO[6];
  #pragma unroll
  for (int j = 0; j < 6; ++j) { sE[j] = 0.f; sO[j] = 0.f; }
  float s_last = 0.f;

  auto step = [&](int tau, bool emit) {
    float uO = 0.f, uE = 0.f;
    #pragma unroll
    for (int j = 0; j < 6; ++j) { uO += F.g1[j] * xw[j]; uE += F.g0[j] * xw[j]; }
    float so = __sinf(uO * av); float sOn = uO + ib * so * so;
    float se = __sinf(uE * av); float sEn = uE + ib * se * se;
    if (tau + 2 == TN_ - 1) s_last = sOn;       // s_odd(T-1) = s[2T-1]
    if (tau + 2 >= TN_) sOn = s_last;
    if (tau + 3 >= TN_) sEn = s_last;
    #pragma unroll
    for (int j = 0; j < 5; ++j) { sE[j] = sE[j + 1]; sO[j] = sO[j + 1]; }
    sE[5] = sEn; sO[5] = sOn;
    if (emit) {
      float d = 0.f;
      #pragma unroll
      for (int j = 0; j < 6; ++j) d += F.fE[j] * sE[j] + F.fO[j] * sO[j];
      d *= mrow[tau];
      drow[(size_t)(PADR_ + tau) * CN_] = f2bf(d);
    }
    #pragma unroll
    for (int j = 0; j < 5; ++j) xw[j] = xw[j + 1];
    xw[5] = ldx(tau + 6);
  };

  for (int w = 0; w < 5; ++w) step(t0 - 5 + w, false);
  if (t0 == 0) {   // s-index < 0 clamps to s[0] = s_even(0) (held in sE[3])
    float s0 = sE[3];
    sE[1] = s0; sE[2] = s0;
    sO[1] = s0; sO[2] = s0; sO[3] = s0;
  }
  for (int t = t0; t < t0 + 128; ++t) step(t, true);
}

// ---------------------------------------------------------------------------
// Conv as pure GEMM — m201 8-phase port, FIXED (r10 re-read flaw removed).
// K = 3 taps x 512 c = 1536; K-tile kappa = cblk*3 + k (BK=64), tap offset
// folded into A staging source (im2col on the fly). 24 K-tiles = 12 iters
// x 8 phases. Block: 512 thr / 8 waves (2m x 4n), tile 256t x 256o,
// per-wave 128x64, acc[8][4]. LDS 128 KiB (1 block/CU, m201 config).
// Per K-tile, 4 quadrant phases with REGISTER-CACHED fragments (24 ds_read
// total = 384 B/MFMA, optimal):
//   P1: read A0(8)+B0(4) | stage -> BAR -> 16 MFMA Q(0,0)
//   P2: read A1(8)       | stage -> BAR -> 16 MFMA Q(1,0)  [reuse B0]
//   P3: read B1(4)       | stage -> BAR -> 16 MFMA Q(0,1)  [reuse A0]
//   P4: (no reads)       | stage -> BAR -> 16 MFMA Q(1,1)  [reuse A1,B1]
// Stage slots (WAR-verified): P1:A0(kt1) P2:A1(kt1) P3:B0(kt1) P4:B0(kt+2)
// P5:A0(kt+2) P6:A1(kt+2) P7:B1(kt+2) P8:B1(kt1+2). vmcnt(2) only at P4/P8
// (retires exactly the 8 oldest of 10 outstanding). Live VGPR ~225 < 256.
// Swizzle q ^= (row&7) on stage source + ds_read (involution, rule 21).
// Tail iterations stage in-bounds garbage for kappa>=24 (never read).
// MODE 0: bf16 out; 1: bf16 out += bf16 res; 2: f32 [b][512][4096] += res,*mask
// ---------------------------------------------------------------------------
#define HSZ 8192            // half-tile elems (128*64)
#define TSZ 16384           // K-tile elems (256*64)

#define VMCNT(n) asm volatile("s_waitcnt vmcnt(" #n ")" ::: "memory")
#define BAR __builtin_amdgcn_s_barrier()
#define PRIO1 __builtin_amdgcn_s_setprio(1)
#define PRIO0 __builtin_amdgcn_s_setprio(0)

#define READ_A(base, mh, dstA) do { \
    _Pragma("unroll") \
    for (int mi_ = 0; mi_ < 4; ++mi_) { \
      const int row_ = wm * 128 + (mh) * 64 + mi_ * 16 + l15; \
      _Pragma("unroll") \
      for (int kk_ = 0; kk_ < 2; ++kk_) { \
        const int q_ = (q4 + kk_ * 4) ^ (row_ & 7); \
        dstA[mi_][kk_] = __builtin_bit_cast(bf16x8, \
            *(const u16x8*)((base) + (size_t)row_ * 64 + q_ * 8)); \
      } \
    } \
  } while (0)

#define READ_B(base, nh, dstB) do { \
    _Pragma("unroll") \
    for (int ni_ = 0; ni_ < 2; ++ni_) { \
      const int orow_ = wn * 64 + ((nh) * 2 + ni_) * 16 + l15; \
      _Pragma("unroll") \
      for (int kk_ = 0; kk_ < 2; ++kk_) { \
        const int q_ = (q4 + kk_ * 4) ^ (orow_ & 7); \
        dstB[ni_][kk_] = __builtin_bit_cast(bf16x8, \
            *(const u16x8*)((base) + (size_t)orow_ * 64 + q_ * 8)); \
      } \
    } \
  } while (0)

#define MFMA16(a_, b_, mh, nh) do { \
    _Pragma("unroll") \
    for (int mi_ = 0; mi_ < 4; ++mi_) { \
      _Pragma("unroll") \
      for (int ni_ = 0; ni_ < 2; ++ni_) { \
        acc[(mh) * 4 + mi_][(nh) * 2 + ni_] = __builtin_amdgcn_mfma_f32_16x16x32_bf16( \
            a_[mi_][0], b_[ni_][0], acc[(mh) * 4 + mi_][(nh) * 2 + ni_], 0, 0, 0); \
        acc[(mh) * 4 + mi_][(nh) * 2 + ni_] = __builtin_amdgcn_mfma_f32_16x16x32_bf16( \
            a_[mi_][1], b_[ni_][1], acc[(mh) * 4 + mi_][(nh) * 2 + ni_], 0, 0, 0); \
      } \
    } \
  } while (0)

template <int MODE, int DIL>
__global__ __launch_bounds__(512, 2) void conv_kernel(
    const unsigned short* __restrict__ act,   // [b][4112][512] bf16 bits
    const unsigned short* __restrict__ wp,    // [3][512][512] bf16 bits
    const float* __restrict__ bias,           // [512]
    const unsigned short* __restrict__ res,   // [b][4096][512] bf16 (MODE>=1)
    const float* __restrict__ mask,           // [b][4096] (MODE==2)
    void* __restrict__ outp)
{
  __shared__ __align__(16) unsigned short lA[2 * TSZ];   // 64 KiB
  __shared__ __align__(16) unsigned short lB[2 * TSZ];   // 64 KiB

  const int tid = threadIdx.x;
  const int bid = blockIdx.x;
  // XCD-aware decode: bid = ((tile*2 + ob) << 3) | xcd
  const int xcd = bid & 7, j = bid >> 3;
  const int ob = j & 1, tile = j >> 1;
  const int tt = tile * 8 + xcd;            // 0..255 global t-tile
  const int b = tt >> 4;
  const int t0 = (tt & 15) << 8;            // 256 t per block
  const int o0 = ob << 8;                   // 256 o per block

  const int lane = tid & 63;
  const int wave = tid >> 6;
  const int wm = wave >> 2, wn = wave & 3;  // 2m x 4n
  const int l15 = lane & 15, q4 = lane >> 4;

  const f32x4 zero = {0.f, 0.f, 0.f, 0.f};
  f32x4 acc[8][4];
  #pragma unroll
  for (int a = 0; a < 8; ++a)
    #pragma unroll
    for (int n = 0; n < 4; ++n) acc[a][n] = zero;

  // base at padded logical row t0 (padded index t0 + PADR_)
  const unsigned short* aBaseP = act + ((size_t)b * TPAD_ + t0 + PADR_) * CN_;

  unsigned short* const Ab[2] = { lA, lA + TSZ };
  unsigned short* const Bb[2] = { lB, lB + TSZ };

  // stage one 128x64 half-tile of A for K-tile kappa = cblk*3 + k
  auto stageA = [&](unsigned short* bufBase, int kappa, int half) {
    const int cb = kappa / 3, k = kappa - 3 * cb;
    const unsigned short* src = aBaseP
        + (ptrdiff_t)((k - 1) * DIL + half * 128) * CN_ + cb * 64;
    unsigned short* dst = bufBase + (size_t)half * HSZ;
    #pragma unroll
    for (int s = 0; s < 2; ++s) {
      int p = tid + (s << 9);                 // 0..1023, lane-consecutive
      int rih = p >> 3, pq = p & 7;
      int gq = pq ^ (rih & 7);                // (half*128+rih)&7 == rih&7
      gld16(src + (size_t)rih * CN_ + gq * 8, dst + (size_t)p * 8);
    }
  };
  auto stageB = [&](unsigned short* bufBase, int kappa, int half) {
    const int cb = kappa / 3, k = kappa - 3 * cb;
    const unsigned short* src = wp
        + ((size_t)k * CN_ + o0 + half * 128) * CN_ + cb * 64;
    unsigned short* dst = bufBase + (size_t)half * HSZ;
    #pragma unroll
    for (int s = 0; s < 2; ++s) {
      int p = tid + (s << 9);
      int rih = p >> 3, pq = p & 7;
      int gq = pq ^ (rih & 7);
      gld16(src + (size_t)rih * CN_ + gq * 8, dst + (size_t)p * 8);
    }
  };

  // Prologue: A(0), B(0) fully; B1(1) pre-staged (steady-state P8 role).
  stageA(Ab[0], 0, 0); stageA(Ab[0], 0, 1);
  stageB(Bb[0], 0, 0); stageB(Bb[0], 0, 1);
  stageB(Bb[1], 1, 1);
  VMCNT(2);          // retire A(0),B(0); B1(1) stays in flight
  BAR;

  for (int i = 0; i < 12; ++i) {
    const int kt1 = 2 * i + 1, ktn = 2 * i + 2, ktn1 = 2 * i + 3;
    bf16x8 a0[4][2], a1[4][2], b0[2][2], b1[2][2];
    // ---- K-tile kt0 (buffer 0) ----
    // P1
    READ_A(Ab[0], 0, a0); READ_B(Bb[0], 0, b0); stageA(Ab[1], kt1, 0);
    BAR; PRIO1; MFMA16(a0, b0, 0, 0); PRIO0; BAR;
    // P2
    READ_A(Ab[0], 1, a1); stageA(Ab[1], kt1, 1);
    BAR; PRIO1; MFMA16(a1, b0, 1, 0); PRIO0; BAR;
    // P3
    READ_B(Bb[0], 1, b1); stageB(Bb[1], kt1, 0);
    BAR; PRIO1; MFMA16(a0, b1, 0, 1); PRIO0; BAR;
    // P4
    stageB(Bb[0], ktn, 0);
    BAR; PRIO1; MFMA16(a1, b1, 1, 1); PRIO0; VMCNT(2); BAR;
    // ---- K-tile kt1 (buffer 1) ----
    // P5
    READ_A(Ab[1], 0, a0); READ_B(Bb[1], 0, b0); stageA(Ab[0], ktn, 0);
    BAR; PRIO1; MFMA16(a0, b0, 0, 0); PRIO0; BAR;
    // P6
    READ_A(Ab[1], 1, a1); stageA(Ab[0], ktn, 1);
    BAR; PRIO1; MFMA16(a1, b0, 1, 0); PRIO0; BAR;
    // P7
    READ_B(Bb[1], 1, b1); stageB(Bb[0], ktn, 1);
    BAR; PRIO1; MFMA16(a0, b1, 0, 1); PRIO0; BAR;
    // P8
    stageB(Bb[1], ktn1, 1);
    BAR; PRIO1; MFMA16(a1, b1, 1, 1); PRIO0; VMCNT(2); BAR;
  }
  VMCNT(0);   // drain dangling (garbage) stages before epilogue

  // epilogue: D frag: col(=o)=lane&15, row(=t)=(lane>>4)*4 + r
  const int obase = o0 + wn * 64 + l15;
  const int tbase = t0 + wm * 128 + q4 * 4;

  if (MODE == 0) {
    unsigned short* O = (unsigned short*)outp + (size_t)b * TN_ * CN_;
    #pragma unroll
    for (int ni = 0; ni < 4; ++ni) {
      float bv = bias[obase + ni * 16];
      #pragma unroll
      for (int mi = 0; mi < 8; ++mi) {
        #pragma unroll
        for (int r = 0; r < 4; ++r) {
          int t = tbase + mi * 16 + r;
          O[(size_t)t * CN_ + obase + ni * 16] = f2bf(acc[mi][ni][r] + bv);
        }
      }
    }
  } else if (MODE == 1) {
    unsigned short* O = (unsigned short*)outp + (size_t)b * TN_ * CN_;
    const unsigned short* R = res + (size_t)b * TN_ * CN_;
    #pragma unroll
    for (int ni = 0; ni < 4; ++ni) {
      float bv = bias[obase + ni * 16];
      #pragma unroll
      for (int mi = 0; mi < 8; ++mi) {
        #pragma unroll
        for (int r = 0; r < 4; ++r) {
          int t = tbase + mi * 16 + r;
          size_t ix = (size_t)t * CN_ + obase + ni * 16;
          O[ix] = f2bf(acc[mi][ni][r] + bv + bf2f(R[ix]));
        }
      }
    }
  } else {
    float* O = (float*)outp + (size_t)b * CN_ * TN_;   // [o][t]
    const unsigned short* R = res + (size_t)b * TN_ * CN_;
    const float* M = mask + (size_t)b * TN_;
    float bv[4];
    #pragma unroll
    for (int ni = 0; ni < 4; ++ni) bv[ni] = bias[obase + ni * 16];
    #pragma unroll
    for (int mi = 0; mi < 8; ++mi) {
      int t = tbase + mi * 16;
      f32x4 mv = *reinterpret_cast<const f32x4*>(M + t);
      #pragma unroll
      for (int ni = 0; ni < 4; ++ni) {
        f32x4 v;
        #pragma unroll
        for (int r = 0; r < 4; ++r)
          v[r] = (acc[mi][ni][r] + bv[ni] + bf2f(R[(size_t)(t + r) * CN_ + obase + ni * 16])) * mv[r];
        *reinterpret_cast<f32x4*>(O + (size_t)(obase + ni * 16) * TN_ + t) = v;
      }
    }
  }
}

// ---------------------------------------------------------------------------
// Host: BigVGAN kaiser-sinc filter (cutoff .25, hw .3, K=12), double precision
// ---------------------------------------------------------------------------
static double bi0(double x) {
  double s = 1.0, t = 1.0, q = x * x * 0.25;
  for (int k = 1; k < 50; ++k) { t *= q / ((double)k * (double)k); s += t; if (t < 1e-18 * s) break; }
  return s;
}
static void make_filt(AAFilt* F) {
  const double PI = 3.14159265358979323846;
  double A = 2.285 * 5.0 * PI * 1.2 + 7.95;
  double beta;
  if (A > 50.0) beta = 0.1102 * (A - 8.7);
  else if (A >= 21.0) beta = 0.5842 * pow(A - 21.0, 0.4) + 0.07886 * (A - 21.0);
  else beta = 0.0;
  double i0b = bi0(beta);
  double f[12], sum = 0.0;
  for (int n = 0; n < 12; ++n) {
    double xx = 2.0 * n / 11.0 - 1.0;
    double w = bi0(beta * sqrt(fmax(0.0, 1.0 - xx * xx))) / i0b;
    double tt = (double)(n - 6) + 0.5;
    double arg = 0.5 * tt;                       // 2*cutoff*time
    double snc = sin(PI * arg) / (PI * arg);
    f[n] = 0.5 * w * snc;                        // 2*cutoff*w*sinc
    sum += f[n];
  }
  for (int n = 0; n < 12; ++n) f[n] /= sum;
  for (int j = 0; j < 6; ++j) {
    F->g0[j] = (float)(2.0 * f[11 - 2 * j]);     // up even phase
    F->g1[j] = (float)(2.0 * f[10 - 2 * j]);     // up odd phase
    F->fE[j] = (float)f[2 * j + 1];              // down, even s taps
    F->fO[j] = (float)f[2 * j];                  // down, odd s taps
  }
}

// ---------------------------------------------------------------------------
extern "C" void kernel_launch(void* const* d_in, const int* in_sizes, int n_in,
                              void* d_out, int out_size, void* d_ws, size_t ws_size,
                              hipStream_t stream)
{
  (void)in_sizes; (void)n_in; (void)out_size; (void)ws_size;
  const float* x    = (const float*)d_in[0];
  const float* mask = (const float*)d_in[1];
  const float* inA  = (const float*)d_in[2];
  const float* inB  = (const float*)d_in[3];
  const float* outA = (const float*)d_in[4];
  const float* outB = (const float*)d_in[5];
  const float* vin  = (const float*)d_in[6];
  const float* gin  = (const float*)d_in[7];
  const float* bin  = (const float*)d_in[8];
  const float* vout = (const float*)d_in[9];
  const float* gout = (const float*)d_in[10];
  const float* bout = (const float*)d_in[11];

  // ws layout (278,134,784 B):
  //  xta  bf16 [16][4096][512]   67108864 B   (x-chain buffer A)
  //  xtb  bf16 [16][4096][512]   67108864 B   (x-chain buffer B)
  //  actb bf16 [16][4112][512]   67371008 B
  //  y1   bf16 [16][4096][512]   67108864 B
  //  wpk  bf16 [6][3][512][512]   9437184 B
  char* ws = (char*)d_ws;
  unsigned short* xta  = (unsigned short*)ws;
  unsigned short* xtb  = (unsigned short*)(ws + 67108864);
  unsigned short* actb = (unsigned short*)(ws + 134217728);
  unsigned short* y1   = (unsigned short*)(ws + 134217728 + 67371008);
  unsigned short* wpk  = (unsigned short*)(ws + 134217728 + 67371008 + 67108864);

  AAFilt F; make_filt(&F);

  prep_w<<<dim3(512, 6), dim3(256), 0, stream>>>(vin, gin, vout, gout, wpk);
  transpose_in<<<dim3(128, 16, 16), dim3(256), 0, stream>>>(x, xta);

  // i = 0 (dil 1): xta -> xtb
  act_kernel<<<dim3(32, 16), dim3(512), 0, stream>>>(
      xta, actb, inA + 0 * CN_, inB + 0 * CN_, mask, F);
  conv_kernel<0, 1><<<dim3(512), dim3(512), 0, stream>>>(
      actb, wpk + (size_t)0 * 3 * CN_ * CN_, bin + 0 * CN_, nullptr, mask, (void*)y1);
  act_kernel<<<dim3(32, 16), dim3(512), 0, stream>>>(
      y1, actb, outA + 0 * CN_, outB + 0 * CN_, mask, F);
  conv_kernel<1, 1><<<dim3(512), dim3(512), 0, stream>>>(
      actb, wpk + (size_t)1 * 3 * CN_ * CN_, bout + 0 * CN_, xta, mask, (void*)xtb);

  // i = 1 (dil 3): xtb -> xta
  act_kernel<<<dim3(32, 16), dim3(512), 0, stream>>>(
      xtb, actb, inA + 1 * CN_, inB + 1 * CN_, mask, F);
  conv_kernel<0, 3><<<dim3(512), dim3(512), 0, stream>>>(
      actb, wpk + (size_t)2 * 3 * CN_ * CN_, bin + 1 * CN_, nullptr, mask, (void*)y1);
  act_kernel<<<dim3(32, 16), dim3(512), 0, stream>>>(
      y1, actb, outA + 1 * CN_, outB + 1 * CN_, mask, F);
  conv_kernel<1, 1><<<dim3(512), dim3(512), 0, stream>>>(
      actb, wpk + (size_t)3 * 3 * CN_ * CN_, bout + 1 * CN_, xtb, mask, (void*)xta);

  // i = 2 (dil 5): xta -> d_out (f32, original [b][c][t] layout)
  act_kernel<<<dim3(32, 16), dim3(512), 0, stream>>>(
      xta, actb, inA + 2 * CN_, inB + 2 * CN_, mask, F);
  conv_kernel<0, 5><<<dim3(512), dim3(512), 0, stream>>>(
      actb, wpk + (size_t)4 * 3 * CN_ * CN_, bin + 2 * CN_, nullptr, mask, (void*)y1);
  act_kernel<<<dim3(32, 16), dim3(512), 0, stream>>>(
      y1, actb, outA + 2 * CN_, outB + 2 * CN_, mask, F);
  conv_kernel<2, 1><<<dim3(512), dim3(512), 0, stream>>>(
      actb, wpk + (size_t)5 * 3 * CN_ * CN_, bout + 2 * CN_, xta, mask, d_out);
}

// Round 13
// 1109.192 us; speedup vs baseline: 1.0965x; 1.0965x over previous
//
#include <hip/hip_runtime.h>
#include <cmath>

// Problem constants
#define BN_ 16
#define CN_ 512
#define TN_ 4096
#define TPAD_ 4112   // 8 zero pad rows each side (t dim) for conv halo
#define PADR_ 8

typedef float f32x4 __attribute__((ext_vector_type(4)));
typedef __bf16 bf16x8 __attribute__((ext_vector_type(8)));
typedef unsigned short u16x8 __attribute__((ext_vector_type(8)));

struct AAFilt { float g0[6]; float g1[6]; float fE[6]; float fO[6]; };

__device__ __forceinline__ unsigned short f2bf(float f) {
  unsigned u = __builtin_bit_cast(unsigned, f);
  u = (u + 0x7fffu + ((u >> 16) & 1u)) >> 16;   // RNE
  return (unsigned short)u;
}
__device__ __forceinline__ float bf2f(unsigned short h) {
  return __builtin_bit_cast(float, (unsigned)h << 16);
}

__device__ __forceinline__ void gld16(const void* g, void* l) {
  __builtin_amdgcn_global_load_lds((const __attribute__((address_space(1))) void*)g,
                                   (__attribute__((address_space(3))) void*)l,
                                   16, 0, 0);
}

// ---------------------------------------------------------------------------
// Weight prep: W[o] = g[o] * v[o] / ||v[o]||, packed bf16 as [layer][k][o][c]
// ---------------------------------------------------------------------------
__global__ __launch_bounds__(256) void prep_w(
    const float* __restrict__ vin, const float* __restrict__ gin,
    const float* __restrict__ vout, const float* __restrict__ gout,
    unsigned short* __restrict__ wpack)
{
  const int o = blockIdx.x;
  const int l = blockIdx.y;
  const int i = l >> 1, oc = l & 1;
  const float* v = (oc ? vout : vin) + (size_t)i * CN_ * CN_ * 3 + (size_t)o * CN_ * 3;
  const float g = (oc ? gout : gin)[i * CN_ + o];
  const int tid = threadIdx.x;

  float a = 0.f;
  for (int j = tid; j < 1536; j += 256) { float x = v[j]; a += x * x; }
  #pragma unroll
  for (int off = 32; off > 0; off >>= 1) a += __shfl_down(a, off);
  __shared__ float red[4];
  if ((tid & 63) == 0) red[tid >> 6] = a;
  __syncthreads();
  const float tot = red[0] + red[1] + red[2] + red[3];
  const float scale = g / sqrtf(tot);
  unsigned short* wl = wpack + (size_t)l * 3 * CN_ * CN_;
  for (int j = tid; j < 1536; j += 256) {
    int c = j / 3, k = j - 3 * c;           // v layout [o][c][k]
    wl[((size_t)k * CN_ + o) * CN_ + c] = f2bf(v[j] * scale);
  }
}

// ---------------------------------------------------------------------------
// Transpose [b][c][t] f32 -> [b][t][c] bf16  (x-chain is bf16 from here on)
// ---------------------------------------------------------------------------
__global__ __launch_bounds__(256) void transpose_in(
    const float* __restrict__ src, unsigned short* __restrict__ dst)
{
  __shared__ float tile[32][33];
  const int b = blockIdx.z, c0 = blockIdx.y * 32, t0 = blockIdx.x * 32;
  const int tx = threadIdx.x & 31, ty = threadIdx.x >> 5;   // ty 0..7
  const float* s = src + ((size_t)b * CN_ + c0) * TN_ + t0;
  #pragma unroll
  for (int j = 0; j < 32; j += 8) tile[ty + j][tx] = s[(size_t)(ty + j) * TN_ + tx];
  __syncthreads();
  unsigned short* d = dst + ((size_t)b * TN_ + t0) * CN_ + c0;
  #pragma unroll
  for (int j = 0; j < 32; j += 8) d[(size_t)(ty + j) * CN_ + tx] = f2bf(tile[tx][ty + j]);
}

// ---------------------------------------------------------------------------
// Alias-free snake activation, streaming along t. bf16 in/out. (r9, unchanged)
// ---------------------------------------------------------------------------
__global__ __launch_bounds__(512) void act_kernel(
    const unsigned short* __restrict__ src, unsigned short* __restrict__ dst,
    const float* __restrict__ alpha, const float* __restrict__ beta,
    const float* __restrict__ mask, AAFilt F)
{
  const int c = threadIdx.x;       // 0..511
  const int b = blockIdx.y;        // 0..15
  const int seg = blockIdx.x;      // 0..31
  const int t0 = seg << 7;         // 128 t per block
  const float av = expf(alpha[c]);
  const float ib = 1.0f / (expf(beta[c]) + 1e-5f);
  const unsigned short* row = src + (size_t)b * TN_ * CN_ + c;
  unsigned short* drow = dst + (size_t)b * TPAD_ * CN_ + c;
  const float* mrow = mask + (size_t)b * TN_;

  if (seg == 0)  { for (int p = 0; p < PADR_; ++p) drow[(size_t)p * CN_] = 0; }
  if (seg == 31) { for (int p = 0; p < PADR_; ++p) drow[(size_t)(TPAD_ - PADR_ + p) * CN_] = 0; }

  auto ldx = [&](int t) -> float {
    t = t < 0 ? 0 : (t > TN_ - 1 ? TN_ - 1 : t);
    return bf2f(row[(size_t)t * CN_]);
  };

  float xw[6];
  #pragma unroll
  for (int j = 0; j < 6; ++j) xw[j] = ldx(t0 - 5 + j);
  float sE[6], sO[6];
  #pragma unroll
  for (int j = 0; j < 6; ++j) { sE[j] = 0.f; sO[j] = 0.f; }
  float s_last = 0.f;

  auto step = [&](int tau, bool emit) {
    float uO = 0.f, uE = 0.f;
    #pragma unroll
    for (int j = 0; j < 6; ++j) { uO += F.g1[j] * xw[j]; uE += F.g0[j] * xw[j]; }
    float so = __sinf(uO * av); float sOn = uO + ib * so * so;
    float se = __sinf(uE * av); float sEn = uE + ib * se * se;
    if (tau + 2 == TN_ - 1) s_last = sOn;       // s_odd(T-1) = s[2T-1]
    if (tau + 2 >= TN_) sOn = s_last;
    if (tau + 3 >= TN_) sEn = s_last;
    #pragma unroll
    for (int j = 0; j < 5; ++j) { sE[j] = sE[j + 1]; sO[j] = sO[j + 1]; }
    sE[5] = sEn; sO[5] = sOn;
    if (emit) {
      float d = 0.f;
      #pragma unroll
      for (int j = 0; j < 6; ++j) d += F.fE[j] * sE[j] + F.fO[j] * sO[j];
      d *= mrow[tau];
      drow[(size_t)(PADR_ + tau) * CN_] = f2bf(d);
    }
    #pragma unroll
    for (int j = 0; j < 5; ++j) xw[j] = xw[j + 1];
    xw[5] = ldx(tau + 6);
  };

  for (int w = 0; w < 5; ++w) step(t0 - 5 + w, false);
  if (t0 == 0) {   // s-index < 0 clamps to s[0] = s_even(0) (held in sE[3])
    float s0 = sE[3];
    sE[1] = s0; sE[2] = s0;
    sO[1] = s0; sO[2] = s0; sO[3] = s0;
  }
  for (int t = t0; t < t0 + 128; ++t) step(t, true);
}

// ---------------------------------------------------------------------------
// Implicit-GEMM dilated conv, bf16 MFMA 16x16x32 — r6/r11 counted-vmcnt
// schedule at 128t x 128o tile, 2 INDEPENDENT blocks/CU (the untested cell:
// all prior counted-vmcnt runs used 130 KiB LDS = 1 block/CU lockstep).
// Block: 256 thr / 4 waves (2m x 2n), per-wave 64x64 (acc[4][4]), BK=32,
// dbuf LDS = 67.6 KiB -> 2 blocks/CU; their barriers desync (m114 overlap).
// K-step = 3 regions, stage groups per wave identical to r6 (A=2+1w0,
// B0/B1/B2=2) so the verified vmcnt ledger carries over:
//   T0: reads(4A+4B) | stageA+stageB0(next) -> BAR -> 16 MFMA -> VMCNT(6) -> BAR
//   T1: reads | stageB1(next) -> BAR -> 16 MFMA -> VMCNT(4) -> BAR
//   T2: reads | stageB2(next) -> BAR -> 16 MFMA -> VMCNT(4) -> BAR
// Peeled last K-step: VMCNT(2)/(0). Chunk-XOR swizzle q ^= (row>>1)&3
// (0 conflicts measured r3-r12); gld16 groups lane-consecutive (m104).
// Grid 2048; decode groups the 4 o-siblings of each A-tile on one XCD
// (per-XCD working set: 16 A-tiles x 147KB + B 1.5MB < 4MB L2).
// MODE 0: bf16 out [b][4096][512] (no res)
// MODE 1: bf16 out [b][4096][512], += bf16 res
// MODE 2: f32  out [b][512][4096], += bf16 res, * mask (final layer)
// ---------------------------------------------------------------------------
#define ASZ (144 * 32)          // A buffer elems (bf16)
#define BSZ (3 * 128 * 32)      // B buffer elems

#define VMCNT(n) asm volatile("s_waitcnt vmcnt(" #n ")" ::: "memory")
#define BAR __builtin_amdgcn_s_barrier()
#define PRIO1 __builtin_amdgcn_s_setprio(1)
#define PRIO0 __builtin_amdgcn_s_setprio(0)

#define READ_A4(k) do { \
    _Pragma("unroll") \
    for (int mi_ = 0; mi_ < 4; ++mi_) { \
      const int r_ = rbase[k] + mi_ * 16; \
      const int q_ = q4 ^ ((r_ >> 1) & 3); \
      af[mi_] = __builtin_bit_cast(bf16x8, \
          *(const u16x8*)(A + ((size_t)r_ * 4 + q_) * 8)); \
    } \
  } while (0)

#define READ_B4(k) do { \
    _Pragma("unroll") \
    for (int ni_ = 0; ni_ < 4; ++ni_) { \
      const int ob_ = wn * 64 + ni_ * 16 + l15; \
      const int q_ = q4 ^ ((ob_ >> 1) & 3); \
      bfr[ni_] = __builtin_bit_cast(bf16x8, \
          *(const u16x8*)(Bc + (((size_t)(k) * 128 + ob_) * 4 + q_) * 8)); \
    } \
  } while (0)

#define MFMA16 do { \
    _Pragma("unroll") \
    for (int mi_ = 0; mi_ < 4; ++mi_) { \
      _Pragma("unroll") \
      for (int ni_ = 0; ni_ < 4; ++ni_) \
        acc[mi_][ni_] = __builtin_amdgcn_mfma_f32_16x16x32_bf16( \
            af[mi_], bfr[ni_], acc[mi_][ni_], 0, 0, 0); \
    } \
  } while (0)

template <int MODE, int DIL>
__global__ __launch_bounds__(256, 2) void conv_kernel(
    const unsigned short* __restrict__ act,   // [b][4112][512] bf16 bits
    const unsigned short* __restrict__ wp,    // [3][512][512] bf16 bits
    const float* __restrict__ bias,           // [512]
    const unsigned short* __restrict__ res,   // [b][4096][512] bf16 (MODE>=1)
    const float* __restrict__ mask,           // [b][4096] (MODE==2)
    void* __restrict__ outp)
{
  __shared__ __align__(16) unsigned short lA[2 * ASZ];
  __shared__ __align__(16) unsigned short lB[2 * BSZ];

  const int tid = threadIdx.x;
  const int bid = blockIdx.x;
  // XCD decode: bid = ((tile*4 + ob) << 3) | xcd ; 4 o-siblings same XCD.
  const int xcd = bid & 7, j = bid >> 3;
  const int ob = j & 3, tile = j >> 2;
  const int tt = tile * 8 + xcd;            // 0..511 global t-tile
  const int b = tt >> 5;
  const int t0 = (tt & 31) << 7;            // 128 t per block
  const int o0 = ob << 7;                   // 128 o per block

  const int lane = tid & 63;
  const int wave = tid >> 6;                // 0..3
  const int wm = wave >> 1, wn = wave & 1;  // 2m x 2n
  const int l15 = lane & 15, q4 = lane >> 4;

  const f32x4 zero = {0.f, 0.f, 0.f, 0.f};
  f32x4 acc[4][4];
  #pragma unroll
  for (int a = 0; a < 4; ++a)
    #pragma unroll
    for (int n = 0; n < 4; ++n) acc[a][n] = zero;

  const unsigned short* aBase = act + ((size_t)b * TPAD_ + t0) * CN_;

  int rbase[3];
  #pragma unroll
  for (int k = 0; k < 3; ++k) rbase[k] = wm * 64 + l15 + PADR_ + (k - 1) * DIL;

  auto stageA = [&](unsigned short* Ad, int c0) {   // 2 sites (+1 for wave 0)
    { int p = tid;       int r = p >> 2, pq = p & 3, gq = pq ^ ((r >> 1) & 3);
      gld16(aBase + (size_t)r * CN_ + c0 + gq * 8, Ad + (size_t)p * 8); }
    { int p = tid + 256; int r = p >> 2, pq = p & 3, gq = pq ^ ((r >> 1) & 3);
      gld16(aBase + (size_t)r * CN_ + c0 + gq * 8, Ad + (size_t)p * 8); }
    if (tid < 64) {   // lane-consecutive tail (gld16 LDS dest = base+lane*16)
      int p = tid + 512;
      int r = p >> 2, pq = p & 3, gq = pq ^ ((r >> 1) & 3);
      gld16(aBase + (size_t)r * CN_ + c0 + gq * 8, Ad + (size_t)p * 8); }
  };
  auto stageB = [&](unsigned short* Bd, int c0, int k) {   // 2 sites
    { int p = tid;       int ol = p >> 2, pq = p & 3, gq = pq ^ ((ol >> 1) & 3);
      gld16(wp + ((size_t)(k * CN_) + o0 + ol) * CN_ + c0 + gq * 8,
            Bd + ((size_t)k * 512 + p) * 8); }
    { int p = tid + 256; int ol = p >> 2, pq = p & 3, gq = pq ^ ((ol >> 1) & 3);
      gld16(wp + ((size_t)(k * CN_) + o0 + ol) * CN_ + c0 + gq * 8,
            Bd + ((size_t)k * 512 + p) * 8); }
  };

  // Prologue: stage K-step 0 in group order {A, B0, B1, B2}; B1,B2 stay in flight.
  stageA(lA, 0); stageB(lB, 0, 0); stageB(lB, 0, 1); stageB(lB, 0, 2);
  VMCNT(4);      // retire A(0)+B0(0); invariant: 4 outstanding {B1,B2}
  BAR;

  for (int cb = 0; cb < 15; ++cb) {
    const unsigned short* A  = lA + (size_t)(cb & 1) * ASZ;
    const unsigned short* Bc = lB + (size_t)(cb & 1) * BSZ;
    unsigned short* An = lA + (size_t)((cb & 1) ^ 1) * ASZ;
    unsigned short* Bn = lB + (size_t)((cb & 1) ^ 1) * BSZ;
    const int c0n = (cb + 1) * 32;
    bf16x8 af[4], bfr[4];
    // T0
    READ_A4(0); READ_B4(0); stageA(An, c0n); stageB(Bn, c0n, 0);
    BAR; PRIO1; MFMA16; PRIO0; VMCNT(6); BAR;
    // T1
    READ_A4(1); READ_B4(1); stageB(Bn, c0n, 1);
    BAR; PRIO1; MFMA16; PRIO0; VMCNT(4); BAR;
    // T2
    READ_A4(2); READ_B4(2); stageB(Bn, c0n, 2);
    BAR; PRIO1; MFMA16; PRIO0; VMCNT(4); BAR;
  }
  { // peeled cb = 15 (no staging; tight drains)
    const unsigned short* A  = lA + ASZ;
    const unsigned short* Bc = lB + BSZ;
    bf16x8 af[4], bfr[4];
    READ_A4(0); READ_B4(0);
    BAR; PRIO1; MFMA16; PRIO0; VMCNT(2); BAR;
    READ_A4(1); READ_B4(1);
    BAR; PRIO1; MFMA16; PRIO0; VMCNT(0); BAR;
    READ_A4(2); READ_B4(2);
    BAR; PRIO1; MFMA16; PRIO0;
  }

  // epilogue: D frag: col(=o)=lane&15, row(=t)=(lane>>4)*4 + r
  const int obase = o0 + wn * 64 + l15;
  const int tbase = t0 + wm * 64 + q4 * 4;

  if (MODE == 0) {
    unsigned short* O = (unsigned short*)outp + (size_t)b * TN_ * CN_;
    #pragma unroll
    for (int ni = 0; ni < 4; ++ni) {
      float bv = bias[obase + ni * 16];
      #pragma unroll
      for (int mi = 0; mi < 4; ++mi) {
        #pragma unroll
        for (int r = 0; r < 4; ++r) {
          int t = tbase + mi * 16 + r;
          O[(size_t)t * CN_ + obase + ni * 16] = f2bf(acc[mi][ni][r] + bv);
        }
      }
    }
  } else if (MODE == 1) {
    unsigned short* O = (unsigned short*)outp + (size_t)b * TN_ * CN_;
    const unsigned short* R = res + (size_t)b * TN_ * CN_;
    #pragma unroll
    for (int ni = 0; ni < 4; ++ni) {
      float bv = bias[obase + ni * 16];
      #pragma unroll
      for (int mi = 0; mi < 4; ++mi) {
        #pragma unroll
        for (int r = 0; r < 4; ++r) {
          int t = tbase + mi * 16 + r;
          size_t ix = (size_t)t * CN_ + obase + ni * 16;
          O[ix] = f2bf(acc[mi][ni][r] + bv + bf2f(R[ix]));
        }
      }
    }
  } else {
    float* O = (float*)outp + (size_t)b * CN_ * TN_;   // [o][t]
    const unsigned short* R = res + (size_t)b * TN_ * CN_;
    const float* M = mask + (size_t)b * TN_;
    float bv[4];
    #pragma unroll
    for (int ni = 0; ni < 4; ++ni) bv[ni] = bias[obase + ni * 16];
    #pragma unroll
    for (int mi = 0; mi < 4; ++mi) {
      int t = tbase + mi * 16;
      f32x4 mv = *reinterpret_cast<const f32x4*>(M + t);
      #pragma unroll
      for (int ni = 0; ni < 4; ++ni) {
        f32x4 v;
        #pragma unroll
        for (int r = 0; r < 4; ++r)
          v[r] = (acc[mi][ni][r] + bv[ni] + bf2f(R[(size_t)(t + r) * CN_ + obase + ni * 16])) * mv[r];
        *reinterpret_cast<f32x4*>(O + (size_t)(obase + ni * 16) * TN_ + t) = v;
      }
    }
  }
}

// ---------------------------------------------------------------------------
// Host: BigVGAN kaiser-sinc filter (cutoff .25, hw .3, K=12), double precision
// ---------------------------------------------------------------------------
static double bi0(double x) {
  double s = 1.0, t = 1.0, q = x * x * 0.25;
  for (int k = 1; k < 50; ++k) { t *= q / ((double)k * (double)k); s += t; if (t < 1e-18 * s) break; }
  return s;
}
static void make_filt(AAFilt* F) {
  const double PI = 3.14159265358979323846;
  double A = 2.285 * 5.0 * PI * 1.2 + 7.95;
  double beta;
  if (A > 50.0) beta = 0.1102 * (A - 8.7);
  else if (A >= 21.0) beta = 0.5842 * pow(A - 21.0, 0.4) + 0.07886 * (A - 21.0);
  else beta = 0.0;
  double i0b = bi0(beta);
  double f[12], sum = 0.0;
  for (int n = 0; n < 12; ++n) {
    double xx = 2.0 * n / 11.0 - 1.0;
    double w = bi0(beta * sqrt(fmax(0.0, 1.0 - xx * xx))) / i0b;
    double tt = (double)(n - 6) + 0.5;
    double arg = 0.5 * tt;                       // 2*cutoff*time
    double snc = sin(PI * arg) / (PI * arg);
    f[n] = 0.5 * w * snc;                        // 2*cutoff*w*sinc
    sum += f[n];
  }
  for (int n = 0; n < 12; ++n) f[n] /= sum;
  for (int j = 0; j < 6; ++j) {
    F->g0[j] = (float)(2.0 * f[11 - 2 * j]);     // up even phase
    F->g1[j] = (float)(2.0 * f[10 - 2 * j]);     // up odd phase
    F->fE[j] = (float)f[2 * j + 1];              // down, even s taps
    F->fO[j] = (float)f[2 * j];                  // down, odd s taps
  }
}

// ---------------------------------------------------------------------------
extern "C" void kernel_launch(void* const* d_in, const int* in_sizes, int n_in,
                              void* d_out, int out_size, void* d_ws, size_t ws_size,
                              hipStream_t stream)
{
  (void)in_sizes; (void)n_in; (void)out_size; (void)ws_size;
  const float* x    = (const float*)d_in[0];
  const float* mask = (const float*)d_in[1];
  const float* inA  = (const float*)d_in[2];
  const float* inB  = (const float*)d_in[3];
  const float* outA = (const float*)d_in[4];
  const float* outB = (const float*)d_in[5];
  const float* vin  = (const float*)d_in[6];
  const float* gin  = (const float*)d_in[7];
  const float* bin  = (const float*)d_in[8];
  const float* vout = (const float*)d_in[9];
  const float* gout = (const float*)d_in[10];
  const float* bout = (const float*)d_in[11];

  // ws layout (278,134,784 B):
  //  xta  bf16 [16][4096][512]   67108864 B   (x-chain buffer A)
  //  xtb  bf16 [16][4096][512]   67108864 B   (x-chain buffer B)
  //  actb bf16 [16][4112][512]   67371008 B
  //  y1   bf16 [16][4096][512]   67108864 B
  //  wpk  bf16 [6][3][512][512]   9437184 B
  char* ws = (char*)d_ws;
  unsigned short* xta  = (unsigned short*)ws;
  unsigned short* xtb  = (unsigned short*)(ws + 67108864);
  unsigned short* actb = (unsigned short*)(ws + 134217728);
  unsigned short* y1   = (unsigned short*)(ws + 134217728 + 67371008);
  unsigned short* wpk  = (unsigned short*)(ws + 134217728 + 67371008 + 67108864);

  AAFilt F; make_filt(&F);

  prep_w<<<dim3(512, 6), dim3(256), 0, stream>>>(vin, gin, vout, gout, wpk);
  transpose_in<<<dim3(128, 16, 16), dim3(256), 0, stream>>>(x, xta);

  // i = 0 (dil 1): xta -> xtb
  act_kernel<<<dim3(32, 16), dim3(512), 0, stream>>>(
      xta, actb, inA + 0 * CN_, inB + 0 * CN_, mask, F);
  conv_kernel<0, 1><<<dim3(2048), dim3(256), 0, stream>>>(
      actb, wpk + (size_t)0 * 3 * CN_ * CN_, bin + 0 * CN_, nullptr, mask, (void*)y1);
  act_kernel<<<dim3(32, 16), dim3(512), 0, stream>>>(
      y1, actb, outA + 0 * CN_, outB + 0 * CN_, mask, F);
  conv_kernel<1, 1><<<dim3(2048), dim3(256), 0, stream>>>(
      actb, wpk + (size_t)1 * 3 * CN_ * CN_, bout + 0 * CN_, xta, mask, (void*)xtb);

  // i = 1 (dil 3): xtb -> xta
  act_kernel<<<dim3(32, 16), dim3(512), 0, stream>>>(
      xtb, actb, inA + 1 * CN_, inB + 1 * CN_, mask, F);
  conv_kernel<0, 3><<<dim3(2048), dim3(256), 0, stream>>>(
      actb, wpk + (size_t)2 * 3 * CN_ * CN_, bin + 1 * CN_, nullptr, mask, (void*)y1);
  act_kernel<<<dim3(32, 16), dim3(512), 0, stream>>>(
      y1, actb, outA + 1 * CN_, outB + 1 * CN_, mask, F);
  conv_kernel<1, 1><<<dim3(2048), dim3(256), 0, stream>>>(
      actb, wpk + (size_t)3 * 3 * CN_ * CN_, bout + 1 * CN_, xtb, mask, (void*)xta);

  // i = 2 (dil 5): xta -> d_out (f32, original [b][c][t] layout)
  act_kernel<<<dim3(32, 16), dim3(512), 0, stream>>>(
      xta, actb, inA + 2 * CN_, inB + 2 * CN_, mask, F);
  conv_kernel<0, 5><<<dim3(2048), dim3(256), 0, stream>>>(
      actb, wpk + (size_t)4 * 3 * CN_ * CN_, bin + 2 * CN_, nullptr, mask, (void*)y1);
  act_kernel<<<dim3(32, 16), dim3(512), 0, stream>>>(
      y1, actb, outA + 2 * CN_, outB + 2 * CN_, mask, F);
  conv_kernel<2, 1><<<dim3(2048), dim3(256), 0, stream>>>(
      actb, wpk + (size_t)5 * 3 * CN_ * CN_, bout + 2 * CN_, xta, mask, d_out);
}

// Round 14
// 1094.031 us; speedup vs baseline: 1.1117x; 1.0139x over previous
//
#include <hip/hip_runtime.h>
#include <cmath>

// Problem constants
#define BN_ 16
#define CN_ 512
#define TN_ 4096
#define TPAD_ 4112   // 8 zero pad rows each side (t dim) for conv halo
#define PADR_ 8

typedef float f32x4 __attribute__((ext_vector_type(4)));
typedef __bf16 bf16x8 __attribute__((ext_vector_type(8)));
typedef unsigned short u16x8 __attribute__((ext_vector_type(8)));

struct AAFilt { float g0[6]; float g1[6]; float fE[6]; float fO[6]; };

__device__ __forceinline__ unsigned short f2bf(float f) {
  unsigned u = __builtin_bit_cast(unsigned, f);
  u = (u + 0x7fffu + ((u >> 16) & 1u)) >> 16;   // RNE
  return (unsigned short)u;
}
__device__ __forceinline__ float bf2f(unsigned short h) {
  return __builtin_bit_cast(float, (unsigned)h << 16);
}

__device__ __forceinline__ void gld16(const void* g, void* l) {
  __builtin_amdgcn_global_load_lds((const __attribute__((address_space(1))) void*)g,
                                   (__attribute__((address_space(3))) void*)l,
                                   16, 0, 0);
}

// ---------------------------------------------------------------------------
// Weight prep: W[o] = g[o] * v[o] / ||v[o]||, packed bf16 as [layer][k][o][c]
// ---------------------------------------------------------------------------
__global__ __launch_bounds__(256) void prep_w(
    const float* __restrict__ vin, const float* __restrict__ gin,
    const float* __restrict__ vout, const float* __restrict__ gout,
    unsigned short* __restrict__ wpack)
{
  const int o = blockIdx.x;
  const int l = blockIdx.y;
  const int i = l >> 1, oc = l & 1;
  const float* v = (oc ? vout : vin) + (size_t)i * CN_ * CN_ * 3 + (size_t)o * CN_ * 3;
  const float g = (oc ? gout : gin)[i * CN_ + o];
  const int tid = threadIdx.x;

  float a = 0.f;
  for (int j = tid; j < 1536; j += 256) { float x = v[j]; a += x * x; }
  #pragma unroll
  for (int off = 32; off > 0; off >>= 1) a += __shfl_down(a, off);
  __shared__ float red[4];
  if ((tid & 63) == 0) red[tid >> 6] = a;
  __syncthreads();
  const float tot = red[0] + red[1] + red[2] + red[3];
  const float scale = g / sqrtf(tot);
  unsigned short* wl = wpack + (size_t)l * 3 * CN_ * CN_;
  for (int j = tid; j < 1536; j += 256) {
    int c = j / 3, k = j - 3 * c;           // v layout [o][c][k]
    wl[((size_t)k * CN_ + o) * CN_ + c] = f2bf(v[j] * scale);
  }
}

// ---------------------------------------------------------------------------
// Transpose [b][c][t] f32 -> [b][t][c] bf16  (x-chain is bf16 from here on)
// ---------------------------------------------------------------------------
__global__ __launch_bounds__(256) void transpose_in(
    const float* __restrict__ src, unsigned short* __restrict__ dst)
{
  __shared__ float tile[32][33];
  const int b = blockIdx.z, c0 = blockIdx.y * 32, t0 = blockIdx.x * 32;
  const int tx = threadIdx.x & 31, ty = threadIdx.x >> 5;   // ty 0..7
  const float* s = src + ((size_t)b * CN_ + c0) * TN_ + t0;
  #pragma unroll
  for (int j = 0; j < 32; j += 8) tile[ty + j][tx] = s[(size_t)(ty + j) * TN_ + tx];
  __syncthreads();
  unsigned short* d = dst + ((size_t)b * TN_ + t0) * CN_ + c0;
  #pragma unroll
  for (int j = 0; j < 32; j += 8) d[(size_t)(ty + j) * CN_ + tx] = f2bf(tile[tx][ty + j]);
}

// ---------------------------------------------------------------------------
// Alias-free snake activation, streaming along t. bf16 in/out. (r9, unchanged)
// ---------------------------------------------------------------------------
__global__ __launch_bounds__(512) void act_kernel(
    const unsigned short* __restrict__ src, unsigned short* __restrict__ dst,
    const float* __restrict__ alpha, const float* __restrict__ beta,
    const float* __restrict__ mask, AAFilt F)
{
  const int c = threadIdx.x;       // 0..511
  const int b = blockIdx.y;        // 0..15
  const int seg = blockIdx.x;      // 0..31
  const int t0 = seg << 7;         // 128 t per block
  const float av = expf(alpha[c]);
  const float ib = 1.0f / (expf(beta[c]) + 1e-5f);
  const unsigned short* row = src + (size_t)b * TN_ * CN_ + c;
  unsigned short* drow = dst + (size_t)b * TPAD_ * CN_ + c;
  const float* mrow = mask + (size_t)b * TN_;

  if (seg == 0)  { for (int p = 0; p < PADR_; ++p) drow[(size_t)p * CN_] = 0; }
  if (seg == 31) { for (int p = 0; p < PADR_; ++p) drow[(size_t)(TPAD_ - PADR_ + p) * CN_] = 0; }

  auto ldx = [&](int t) -> float {
    t = t < 0 ? 0 : (t > TN_ - 1 ? TN_ - 1 : t);
    return bf2f(row[(size_t)t * CN_]);
  };

  float xw[6];
  #pragma unroll
  for (int j = 0; j < 6; ++j) xw[j] = ldx(t0 - 5 + j);
  float sE[6], sO[6];
  #pragma unroll
  for (int j = 0; j < 6; ++j) { sE[j] = 0.f; sO[j] = 0.f; }
  float s_last = 0.f;

  auto step = [&](int tau, bool emit) {
    float uO = 0.f, uE = 0.f;
    #pragma unroll
    for (int j = 0; j < 6; ++j) { uO += F.g1[j] * xw[j]; uE += F.g0[j] * xw[j]; }
    float so = __sinf(uO * av); float sOn = uO + ib * so * so;
    float se = __sinf(uE * av); float sEn = uE + ib * se * se;
    if (tau + 2 == TN_ - 1) s_last = sOn;       // s_odd(T-1) = s[2T-1]
    if (tau + 2 >= TN_) sOn = s_last;
    if (tau + 3 >= TN_) sEn = s_last;
    #pragma unroll
    for (int j = 0; j < 5; ++j) { sE[j] = sE[j + 1]; sO[j] = sO[j + 1]; }
    sE[5] = sEn; sO[5] = sOn;
    if (emit) {
      float d = 0.f;
      #pragma unroll
      for (int j = 0; j < 6; ++j) d += F.fE[j] * sE[j] + F.fO[j] * sO[j];
      d *= mrow[tau];
      drow[(size_t)(PADR_ + tau) * CN_] = f2bf(d);
    }
    #pragma unroll
    for (int j = 0; j < 5; ++j) xw[j] = xw[j + 1];
    xw[5] = ldx(tau + 6);
  };

  for (int w = 0; w < 5; ++w) step(t0 - 5 + w, false);
  if (t0 == 0) {   // s-index < 0 clamps to s[0] = s_even(0) (held in sE[3])
    float s0 = sE[3];
    sE[1] = s0; sE[2] = s0;
    sO[1] = s0; sO[2] = s0; sO[3] = s0;
  }
  for (int t = t0; t < t0 + 128; ++t) step(t, true);
}

// ---------------------------------------------------------------------------
// Implicit-GEMM dilated conv — r13 structure at 3 blocks/CU via B tap-ring.
// r13 (2 blocks/CU) proved block desync is the lever (25->31% MfmaUtil).
// This round: B LDS = ring of 4 tap-slots (slot = (3cb+k)&3; stage into
// (tau+3)&3, 3 regions ahead of its read) instead of a full 3-tap dbuf:
// 49KB -> 32KB. Total LDS 51.2KB -> 3 blocks/CU (12 waves, 3/SIMD).
// WAR: staged slot was last read one barrier earlier (reads land in regs
// before that barrier). A stays dbuf. Block: 256 thr / 4 waves (2m x 2n),
// tile 128t x 128o, BK=32. Ring vmcnt ledger (per-wave, wave0-safe):
//   T0: reads | stageA(next)+stageB(tau+3) -> BAR -> 16 MFMA -> VMCNT(6) -> BAR
//   T1: reads | stageB(tau+3) -> BAR -> 16 MFMA -> VMCNT(6) -> BAR
//   T2: reads | stageB(tau+3) -> BAR -> 16 MFMA -> VMCNT(4) -> BAR
// Prologue vmcnt(4); peeled tail vmcnt(2)/(0). Swizzle q^=(row>>1)&3
// (0 conflicts r3-r13); gld16 lane-consecutive (m104). Grid 2048, XCD
// decode groups 4 o-siblings per A-tile.
// MODE 0: bf16 out; 1: bf16 out += bf16 res; 2: f32 [b][512][4096] += res,*mask
// ---------------------------------------------------------------------------
#define ASZ (144 * 32)          // A buffer elems (bf16)
#define BSLOT (128 * 32)        // B ring slot elems

#define VMCNT(n) asm volatile("s_waitcnt vmcnt(" #n ")" ::: "memory")
#define BAR __builtin_amdgcn_s_barrier()
#define PRIO1 __builtin_amdgcn_s_setprio(1)
#define PRIO0 __builtin_amdgcn_s_setprio(0)

#define READ_A4(k) do { \
    _Pragma("unroll") \
    for (int mi_ = 0; mi_ < 4; ++mi_) { \
      const int r_ = rbase[k] + mi_ * 16; \
      const int q_ = q4 ^ ((r_ >> 1) & 3); \
      af[mi_] = __builtin_bit_cast(bf16x8, \
          *(const u16x8*)(A + ((size_t)r_ * 4 + q_) * 8)); \
    } \
  } while (0)

#define READ_B4(slot) do { \
    const unsigned short* Bs_ = lB + (size_t)(slot) * BSLOT; \
    _Pragma("unroll") \
    for (int ni_ = 0; ni_ < 4; ++ni_) { \
      const int ob_ = wn * 64 + ni_ * 16 + l15; \
      const int q_ = q4 ^ ((ob_ >> 1) & 3); \
      bfr[ni_] = __builtin_bit_cast(bf16x8, \
          *(const u16x8*)(Bs_ + ((size_t)ob_ * 4 + q_) * 8)); \
    } \
  } while (0)

#define MFMA16 do { \
    _Pragma("unroll") \
    for (int mi_ = 0; mi_ < 4; ++mi_) { \
      _Pragma("unroll") \
      for (int ni_ = 0; ni_ < 4; ++ni_) \
        acc[mi_][ni_] = __builtin_amdgcn_mfma_f32_16x16x32_bf16( \
            af[mi_], bfr[ni_], acc[mi_][ni_], 0, 0, 0); \
    } \
  } while (0)

template <int MODE, int DIL>
__global__ __launch_bounds__(256, 3) void conv_kernel(
    const unsigned short* __restrict__ act,   // [b][4112][512] bf16 bits
    const unsigned short* __restrict__ wp,    // [3][512][512] bf16 bits
    const float* __restrict__ bias,           // [512]
    const unsigned short* __restrict__ res,   // [b][4096][512] bf16 (MODE>=1)
    const float* __restrict__ mask,           // [b][4096] (MODE==2)
    void* __restrict__ outp)
{
  __shared__ __align__(16) unsigned short lA[2 * ASZ];     // 18.4 KB
  __shared__ __align__(16) unsigned short lB[4 * BSLOT];   // 32 KB

  const int tid = threadIdx.x;
  const int bid = blockIdx.x;
  // XCD decode: bid = ((tile*4 + ob) << 3) | xcd ; 4 o-siblings same XCD.
  const int xcd = bid & 7, j = bid >> 3;
  const int ob = j & 3, tile = j >> 2;
  const int tt = tile * 8 + xcd;            // 0..511 global t-tile
  const int b = tt >> 5;
  const int t0 = (tt & 31) << 7;            // 128 t per block
  const int o0 = ob << 7;                   // 128 o per block

  const int lane = tid & 63;
  const int wave = tid >> 6;                // 0..3
  const int wm = wave >> 1, wn = wave & 1;  // 2m x 2n
  const int l15 = lane & 15, q4 = lane >> 4;

  const f32x4 zero = {0.f, 0.f, 0.f, 0.f};
  f32x4 acc[4][4];
  #pragma unroll
  for (int a = 0; a < 4; ++a)
    #pragma unroll
    for (int n = 0; n < 4; ++n) acc[a][n] = zero;

  const unsigned short* aBase = act + ((size_t)b * TPAD_ + t0) * CN_;

  int rbase[3];
  #pragma unroll
  for (int k = 0; k < 3; ++k) rbase[k] = wm * 64 + l15 + PADR_ + (k - 1) * DIL;

  auto stageA = [&](unsigned short* Ad, int c0) {   // 2 sites (+1 for wave 0)
    { int p = tid;       int r = p >> 2, pq = p & 3, gq = pq ^ ((r >> 1) & 3);
      gld16(aBase + (size_t)r * CN_ + c0 + gq * 8, Ad + (size_t)p * 8); }
    { int p = tid + 256; int r = p >> 2, pq = p & 3, gq = pq ^ ((r >> 1) & 3);
      gld16(aBase + (size_t)r * CN_ + c0 + gq * 8, Ad + (size_t)p * 8); }
    if (tid < 64) {   // lane-consecutive tail (gld16 LDS dest = base+lane*16)
      int p = tid + 512;
      int r = p >> 2, pq = p & 3, gq = pq ^ ((r >> 1) & 3);
      gld16(aBase + (size_t)r * CN_ + c0 + gq * 8, Ad + (size_t)p * 8); }
  };
  auto stageB = [&](int slot, int c0, int k) {   // 2 sites into ring slot
    unsigned short* Bd = lB + (size_t)slot * BSLOT;
    { int p = tid;       int ol = p >> 2, pq = p & 3, gq = pq ^ ((ol >> 1) & 3);
      gld16(wp + ((size_t)(k * CN_) + o0 + ol) * CN_ + c0 + gq * 8,
            Bd + (size_t)p * 8); }
    { int p = tid + 256; int ol = p >> 2, pq = p & 3, gq = pq ^ ((ol >> 1) & 3);
      gld16(wp + ((size_t)(k * CN_) + o0 + ol) * CN_ + c0 + gq * 8,
            Bd + (size_t)p * 8); }
  };

  // Prologue: A(0) + B taps tau=0,1,2 into ring slots 0,1,2.
  stageA(lA, 0);
  stageB(0, 0, 0); stageB(1, 0, 1); stageB(2, 0, 2);
  VMCNT(4);      // retire A(0)+B(tau=0); tau=1,2 stay in flight
  BAR;

  for (int cb = 0; cb < 15; ++cb) {
    const unsigned short* A = lA + (size_t)(cb & 1) * ASZ;
    unsigned short* An = lA + (size_t)((cb & 1) ^ 1) * ASZ;
    const int c0n = (cb + 1) * 32;
    const int tau = 3 * cb;                  // tap index of T0
    bf16x8 af[4], bfr[4];
    // T0 (reads tap tau, slot tau&3; stages A(next) + tap tau+3 -> slot (tau+3)&3)
    READ_A4(0); READ_B4(tau & 3);
    stageA(An, c0n); stageB((tau + 3) & 3, c0n, 0);
    BAR; PRIO1; MFMA16; PRIO0; VMCNT(6); BAR;
    // T1 (reads tap tau+1; stages tap tau+4)
    READ_A4(1); READ_B4((tau + 1) & 3);
    stageB((tau + 4) & 3, c0n, 1);
    BAR; PRIO1; MFMA16; PRIO0; VMCNT(6); BAR;
    // T2 (reads tap tau+2; stages tap tau+5)
    READ_A4(2); READ_B4((tau + 2) & 3);
    stageB((tau + 5) & 3, c0n, 2);
    BAR; PRIO1; MFMA16; PRIO0; VMCNT(4); BAR;
  }
  { // peeled cb = 15 (no staging; tight drains)
    const unsigned short* A = lA + ASZ;
    const int tau = 45;
    bf16x8 af[4], bfr[4];
    READ_A4(0); READ_B4(tau & 3);
    BAR; PRIO1; MFMA16; PRIO0; VMCNT(2); BAR;
    READ_A4(1); READ_B4((tau + 1) & 3);
    BAR; PRIO1; MFMA16; PRIO0; VMCNT(0); BAR;
    READ_A4(2); READ_B4((tau + 2) & 3);
    BAR; PRIO1; MFMA16; PRIO0;
  }

  // epilogue: D frag: col(=o)=lane&15, row(=t)=(lane>>4)*4 + r
  const int obase = o0 + wn * 64 + l15;
  const int tbase = t0 + wm * 64 + q4 * 4;

  if (MODE == 0) {
    unsigned short* O = (unsigned short*)outp + (size_t)b * TN_ * CN_;
    #pragma unroll
    for (int ni = 0; ni < 4; ++ni) {
      float bv = bias[obase + ni * 16];
      #pragma unroll
      for (int mi = 0; mi < 4; ++mi) {
        #pragma unroll
        for (int r = 0; r < 4; ++r) {
          int t = tbase + mi * 16 + r;
          O[(size_t)t * CN_ + obase + ni * 16] = f2bf(acc[mi][ni][r] + bv);
        }
      }
    }
  } else if (MODE == 1) {
    unsigned short* O = (unsigned short*)outp + (size_t)b * TN_ * CN_;
    const unsigned short* R = res + (size_t)b * TN_ * CN_;
    #pragma unroll
    for (int ni = 0; ni < 4; ++ni) {
      float bv = bias[obase + ni * 16];
      #pragma unroll
      for (int mi = 0; mi < 4; ++mi) {
        #pragma unroll
        for (int r = 0; r < 4; ++r) {
          int t = tbase + mi * 16 + r;
          size_t ix = (size_t)t * CN_ + obase + ni * 16;
          O[ix] = f2bf(acc[mi][ni][r] + bv + bf2f(R[ix]));
        }
      }
    }
  } else {
    float* O = (float*)outp + (size_t)b * CN_ * TN_;   // [o][t]
    const unsigned short* R = res + (size_t)b * TN_ * CN_;
    const float* M = mask + (size_t)b * TN_;
    float bv[4];
    #pragma unroll
    for (int ni = 0; ni < 4; ++ni) bv[ni] = bias[obase + ni * 16];
    #pragma unroll
    for (int mi = 0; mi < 4; ++mi) {
      int t = tbase + mi * 16;
      f32x4 mv = *reinterpret_cast<const f32x4*>(M + t);
      #pragma unroll
      for (int ni = 0; ni < 4; ++ni) {
        f32x4 v;
        #pragma unroll
        for (int r = 0; r < 4; ++r)
          v[r] = (acc[mi][ni][r] + bv[ni] + bf2f(R[(size_t)(t + r) * CN_ + obase + ni * 16])) * mv[r];
        *reinterpret_cast<f32x4*>(O + (size_t)(obase + ni * 16) * TN_ + t) = v;
      }
    }
  }
}

// ---------------------------------------------------------------------------
// Host: BigVGAN kaiser-sinc filter (cutoff .25, hw .3, K=12), double precision
// ---------------------------------------------------------------------------
static double bi0(double x) {
  double s = 1.0, t = 1.0, q = x * x * 0.25;
  for (int k = 1; k < 50; ++k) { t *= q / ((double)k * (double)k); s += t; if (t < 1e-18 * s) break; }
  return s;
}
static void make_filt(AAFilt* F) {
  const double PI = 3.14159265358979323846;
  double A = 2.285 * 5.0 * PI * 1.2 + 7.95;
  double beta;
  if (A > 50.0) beta = 0.1102 * (A - 8.7);
  else if (A >= 21.0) beta = 0.5842 * pow(A - 21.0, 0.4) + 0.07886 * (A - 21.0);
  else beta = 0.0;
  double i0b = bi0(beta);
  double f[12], sum = 0.0;
  for (int n = 0; n < 12; ++n) {
    double xx = 2.0 * n / 11.0 - 1.0;
    double w = bi0(beta * sqrt(fmax(0.0, 1.0 - xx * xx))) / i0b;
    double tt = (double)(n - 6) + 0.5;
    double arg = 0.5 * tt;                       // 2*cutoff*time
    double snc = sin(PI * arg) / (PI * arg);
    f[n] = 0.5 * w * snc;                        // 2*cutoff*w*sinc
    sum += f[n];
  }
  for (int n = 0; n < 12; ++n) f[n] /= sum;
  for (int j = 0; j < 6; ++j) {
    F->g0[j] = (float)(2.0 * f[11 - 2 * j]);     // up even phase
    F->g1[j] = (float)(2.0 * f[10 - 2 * j]);     // up odd phase
    F->fE[j] = (float)f[2 * j + 1];              // down, even s taps
    F->fO[j] = (float)f[2 * j];                  // down, odd s taps
  }
}

// ---------------------------------------------------------------------------
extern "C" void kernel_launch(void* const* d_in, const int* in_sizes, int n_in,
                              void* d_out, int out_size, void* d_ws, size_t ws_size,
                              hipStream_t stream)
{
  (void)in_sizes; (void)n_in; (void)out_size; (void)ws_size;
  const float* x    = (const float*)d_in[0];
  const float* mask = (const float*)d_in[1];
  const float* inA  = (const float*)d_in[2];
  const float* inB  = (const float*)d_in[3];
  const float* outA = (const float*)d_in[4];
  const float* outB = (const float*)d_in[5];
  const float* vin  = (const float*)d_in[6];
  const float* gin  = (const float*)d_in[7];
  const float* bin  = (const float*)d_in[8];
  const float* vout = (const float*)d_in[9];
  const float* gout = (const float*)d_in[10];
  const float* bout = (const float*)d_in[11];

  // ws layout (278,134,784 B):
  //  xta  bf16 [16][4096][512]   67108864 B   (x-chain buffer A)
  //  xtb  bf16 [16][4096][512]   67108864 B   (x-chain buffer B)
  //  actb bf16 [16][4112][512]   67371008 B
  //  y1   bf16 [16][4096][512]   67108864 B
  //  wpk  bf16 [6][3][512][512]   9437184 B
  char* ws = (char*)d_ws;
  unsigned short* xta  = (unsigned short*)ws;
  unsigned short* xtb  = (unsigned short*)(ws + 67108864);
  unsigned short* actb = (unsigned short*)(ws + 134217728);
  unsigned short* y1   = (unsigned short*)(ws + 134217728 + 67371008);
  unsigned short* wpk  = (unsigned short*)(ws + 134217728 + 67371008 + 67108864);

  AAFilt F; make_filt(&F);

  prep_w<<<dim3(512, 6), dim3(256), 0, stream>>>(vin, gin, vout, gout, wpk);
  transpose_in<<<dim3(128, 16, 16), dim3(256), 0, stream>>>(x, xta);

  // i = 0 (dil 1): xta -> xtb
  act_kernel<<<dim3(32, 16), dim3(512), 0, stream>>>(
      xta, actb, inA + 0 * CN_, inB + 0 * CN_, mask, F);
  conv_kernel<0, 1><<<dim3(2048), dim3(256), 0, stream>>>(
      actb, wpk + (size_t)0 * 3 * CN_ * CN_, bin + 0 * CN_, nullptr, mask, (void*)y1);
  act_kernel<<<dim3(32, 16), dim3(512), 0, stream>>>(
      y1, actb, outA + 0 * CN_, outB + 0 * CN_, mask, F);
  conv_kernel<1, 1><<<dim3(2048), dim3(256), 0, stream>>>(
      actb, wpk + (size_t)1 * 3 * CN_ * CN_, bout + 0 * CN_, xta, mask, (void*)xtb);

  // i = 1 (dil 3): xtb -> xta
  act_kernel<<<dim3(32, 16), dim3(512), 0, stream>>>(
      xtb, actb, inA + 1 * CN_, inB + 1 * CN_, mask, F);
  conv_kernel<0, 3><<<dim3(2048), dim3(256), 0, stream>>>(
      actb, wpk + (size_t)2 * 3 * CN_ * CN_, bin + 1 * CN_, nullptr, mask, (void*)y1);
  act_kernel<<<dim3(32, 16), dim3(512), 0, stream>>>(
      y1, actb, outA + 1 * CN_, outB + 1 * CN_, mask, F);
  conv_kernel<1, 1><<<dim3(2048), dim3(256), 0, stream>>>(
      actb, wpk + (size_t)3 * 3 * CN_ * CN_, bout + 1 * CN_, xtb, mask, (void*)xta);

  // i = 2 (dil 5): xta -> d_out (f32, original [b][c][t] layout)
  act_kernel<<<dim3(32, 16), dim3(512), 0, stream>>>(
      xta, actb, inA + 2 * CN_, inB + 2 * CN_, mask, F);
  conv_kernel<0, 5><<<dim3(2048), dim3(256), 0, stream>>>(
      actb, wpk + (size_t)4 * 3 * CN_ * CN_, bin + 2 * CN_, nullptr, mask, (void*)y1);
  act_kernel<<<dim3(32, 16), dim3(512), 0, stream>>>(
      y1, actb, outA + 2 * CN_, outB + 2 * CN_, mask, F);
  conv_kernel<2, 1><<<dim3(2048), dim3(256), 0, stream>>>(
      actb, wpk + (size_t)5 * 3 * CN_ * CN_, bout + 2 * CN_, xta, mask, d_out);
}